// Round 7
// baseline (188.258 us; speedup 1.0000x reference)
//
#include <hip/hip_runtime.h>
#include <hip/hip_bf16.h>

#define D 256
#define TWOD 512
#define BM 128
#define BK 32

typedef __attribute__((ext_vector_type(8))) __bf16 bf16x8;
typedef __attribute__((ext_vector_type(4))) float f32x4;
typedef __attribute__((ext_vector_type(8))) unsigned short ushort8;

using as1_u32 = __attribute__((address_space(1))) const unsigned int;
using as3_u32 = __attribute__((address_space(3))) unsigned int;

__device__ __forceinline__ void gload_lds16(const void* g, void* l) {
    __builtin_amdgcn_global_load_lds((as1_u32*)g, (as3_u32*)l, 16, 0, 0);
}

// ---------- helpers ----------
__device__ __forceinline__ float bf2f(unsigned short u) {
    unsigned int x = ((unsigned int)u) << 16;
    return __uint_as_float(x);
}
__device__ __forceinline__ unsigned short f2bf_bits(float f) {
    unsigned int x = __float_as_uint(f);
    unsigned int r = (x + 0x7fffu + ((x >> 16) & 1u)) >> 16;  // RNE
    return (unsigned short)r;
}

// ---------- Kernel 0: w1 (fp32 [256][512]) -> WtP, fragment-packed bf16 ----------
// C column jj in [0,512), k in [0,256):
//   jj<256: element w1[jj][k];  jj>=256: w1[jj-256][256+k]
// Packed so a wave's B-frag (c16 = jj/16, kblk = k/32) is 512 contiguous shorts:
//   WtP[(c16*8 + kblk)*512 + lane*8 + kj], lane = (jj&15) + 16*((k&31)>>3), kj = k&7
__global__ __launch_bounds__(256) void wt_conv_kernel(
    const float* __restrict__ w1, unsigned short* __restrict__ WtP)
{
    const int s = blockIdx.x * 256 + threadIdx.x;   // 0..131071
    const int o = s >> 9;        // w1 row (output unit)
    const int i = s & 511;       // w1 col (input dim)
    const float v = w1[s];
    const int jj = (i < D) ? o : (D + o);
    const int k  = (i < D) ? i : (i - D);
    const int c16 = jj >> 4, r = jj & 15;
    const int kblk = k >> 5, kin = k & 31;
    const int g = kin >> 3, kj = kin & 7;
    WtP[(size_t)((c16 * 8 + kblk) * 512 + (r + 16 * g) * 8 + kj)] = f2bf_bits(v);
}

// ---------- Kernel 1: MFMA node projection ----------
// A-only LDS (2 x 16KB, double-buffered, global_load_lds), B direct from packed
// WtP (L2-resident, coalesced 1KB per frag load). 4 blocks/CU for TLP.
// XCD-pinned columns: all 4 col-blocks of a row-block on one XCD's L2.
__global__ __launch_bounds__(256, 4) void node_proj_mfma(
    const float* __restrict__ z, const unsigned short* __restrict__ WtP,
    unsigned short* __restrict__ C, int M, int Mblocks)
{
    __shared__ __align__(16) float Abuf[2][BM * BK];  // 2 x 16 KB

    const int bid    = blockIdx.x;
    const int rowblk = (bid >> 5) * 8 + (bid & 7);
    if (rowblk >= Mblocks) return;                 // block-uniform
    const int m0 = rowblk * BM;
    const int cb = ((bid >> 3) & 3) * BM;

    const int t    = threadIdx.x;
    const int lane = t & 63;
    const int w    = t >> 6;

    const int r16 = lane & 15;
    const int g   = lane >> 4;       // 0..3

    const int wm = (w >> 1) * 64;    // wave row offset within tile
    const int wn = (w & 1) * 64;     // wave col offset within tile
    const int c16b = (cb + wn) >> 4;

    f32x4 acc[4][4];
    #pragma unroll
    for (int mt = 0; mt < 4; ++mt)
        #pragma unroll
        for (int nt = 0; nt < 4; ++nt)
            acc[mt][nt] = (f32x4){0.f, 0.f, 0.f, 0.f};

    auto stageA = [&](int buf, int k0) {
        // A tile: 128x32 f32 = 1024 16B-chunks, 4 per thread.
        // LDS chunk c = r*8+q holds global col-chunk q^(r&7) of row r.
        #pragma unroll
        for (int i = 0; i < 4; ++i) {
            const int c = i * 256 + t;
            const int r = c >> 3;
            const int q = c & 7;
            const int col = ((q ^ (r & 7)) << 2);
            const int row = min(m0 + r, M - 1);      // clamp: last-block tail
            const float* gsrc = z + (size_t)row * D + k0 + col;
            float* ldst = &Abuf[buf][(size_t)(i * 256 + w * 64) * 4]; // wave-uniform base
            gload_lds16(gsrc, ldst);
        }
    };

    stageA(0, 0);
    __syncthreads();

    int buf = 0;
    #pragma unroll
    for (int kt = 0; kt < 8; ++kt) {
        if (kt < 7) stageA(buf ^ 1, (kt + 1) * BK);   // prefetch next K-tile

        // B fragments: direct coalesced loads from packed Wt (L2-resident)
        bf16x8 b[4];
        #pragma unroll
        for (int nt = 0; nt < 4; ++nt) {
            const ushort8 bu = *(const ushort8*)(
                WtP + (size_t)(((c16b + nt) * 8 + kt) * 512 + lane * 8));
            b[nt] = __builtin_bit_cast(bf16x8, bu);
        }
        // A fragments (fp32 -> bf16 in-register, swizzled LDS read)
        bf16x8 a[4];
        #pragma unroll
        for (int mt = 0; mt < 4; ++mt) {
            const int rl = wm + mt * 16 + r16;
            const int s = rl & 7;
            const f32x4 f0 = *(const f32x4*)&Abuf[buf][rl * 32 + (((2 * g) ^ s) << 2)];
            const f32x4 f1 = *(const f32x4*)&Abuf[buf][rl * 32 + (((2 * g + 1) ^ s) << 2)];
            bf16x8 tt;
            tt[0] = (__bf16)f0[0]; tt[1] = (__bf16)f0[1];
            tt[2] = (__bf16)f0[2]; tt[3] = (__bf16)f0[3];
            tt[4] = (__bf16)f1[0]; tt[5] = (__bf16)f1[1];
            tt[6] = (__bf16)f1[2]; tt[7] = (__bf16)f1[3];
            a[mt] = tt;
        }

        __builtin_amdgcn_s_setprio(1);
        #pragma unroll
        for (int nt = 0; nt < 4; ++nt)
            #pragma unroll
            for (int mt = 0; mt < 4; ++mt)
                acc[mt][nt] = __builtin_amdgcn_mfma_f32_16x16x32_bf16(
                    b[nt], a[mt], acc[mt][nt], 0, 0, 0);
        __builtin_amdgcn_s_setprio(0);

        __syncthreads();   // drains prefetch vmcnt + retires LDS reads
        buf ^= 1;
    }

    // Store: lane holds 4 consecutive C-columns for one row.
    #pragma unroll
    for (int mt = 0; mt < 4; ++mt) {
        const int row = m0 + wm + mt * 16 + r16;
        if (row < M) {
            #pragma unroll
            for (int nt = 0; nt < 4; ++nt) {
                const int col = cb + wn + nt * 16 + g * 4;
                ushort4 pk;
                pk.x = f2bf_bits(acc[mt][nt][0]);
                pk.y = f2bf_bits(acc[mt][nt][1]);
                pk.z = f2bf_bits(acc[mt][nt][2]);
                pk.w = f2bf_bits(acc[mt][nt][3]);
                *(ushort4*)(C + (size_t)row * TWOD + col) = pk;
            }
        }
    }
}

// ---------- Sort kernels: group edges by source node u ----------
__global__ __launch_bounds__(256) void hist_kernel(
    const int* __restrict__ ei, int* __restrict__ counts, int E)
{
    const int e = blockIdx.x * 256 + threadIdx.x;
    if (e < E) atomicAdd(&counts[ei[e]], 1);
}

__global__ __launch_bounds__(1024) void scan_kernel(
    const int* __restrict__ counts, int* __restrict__ offsets, int N)
{
    __shared__ int ps[1024];
    const int t = threadIdx.x;
    const int chunk = (N + 1023) / 1024;
    const int lo = t * chunk;
    const int hi = min(lo + chunk, N);
    int s = 0;
    for (int i = lo; i < hi; ++i) s += counts[i];
    ps[t] = s;
    __syncthreads();
    for (int off = 1; off < 1024; off <<= 1) {
        int v = (t >= off) ? ps[t - off] : 0;
        __syncthreads();
        ps[t] += v;
        __syncthreads();
    }
    int run = (t == 0) ? 0 : ps[t - 1];
    for (int i = lo; i < hi; ++i) { offsets[i] = run; run += counts[i]; }
    if (t == 1023) offsets[N] = run;   // = E (chunks past N are empty)
}

__global__ __launch_bounds__(256) void scatter_kernel(
    const int* __restrict__ ei, int* __restrict__ cursor,
    int2* __restrict__ payload, int E)
{
    const int e = blockIdx.x * 256 + threadIdx.x;
    if (e < E) {
        const int u = ei[e];
        const int pos = atomicAdd(&cursor[u], 1);
        payload[pos] = make_int2(ei[E + e], e);
    }
}

// ---------- Kernel 2a: grouped edge relu-dot (half-wave per node u) ----------
// A[u] (+ b1) loaded once into regs, reused over all of u's edges.
__global__ __launch_bounds__(256) void edge_grouped_kernel(
    const int* __restrict__ offsets, const int2* __restrict__ payload,
    const unsigned short* __restrict__ C, const float* __restrict__ b1,
    const float* __restrict__ w2, const float* __restrict__ b2,
    float* __restrict__ out, int N)
{
    const int h = threadIdx.x & 31;
    const int u = (blockIdx.x * 256 + threadIdx.x) >> 5;
    if (u >= N) return;
    const int start = offsets[u];
    const int end   = offsets[u + 1];
    if (start == end) return;
    const int j0 = h * 8;

    const ushort8 ua = *(const ushort8*)(C + (size_t)u * TWOD + j0);
    float af[8], wl[8];
    #pragma unroll
    for (int j = 0; j < 8; ++j) {
        af[j] = bf2f(ua[j]) + b1[j0 + j];
        wl[j] = w2[j0 + j];
    }
    const float b2s = b2[0];
    const unsigned short* Cb = C + D;   // B-half base

    auto edot = [&](int v) -> float {
        const ushort8 ub = *(const ushort8*)(Cb + (size_t)v * TWOD + j0);
        float s = 0.f;
        #pragma unroll
        for (int j = 0; j < 8; ++j)
            s += fmaxf(af[j] + bf2f(ub[j]), 0.f) * wl[j];
        return s;
    };

    int p = start;
    for (; p + 2 <= end; p += 2) {
        const int2 ve0 = payload[p];
        const int2 ve1 = payload[p + 1];
        float s0 = edot(ve0.x);
        float s1 = edot(ve1.x);
        #pragma unroll
        for (int off = 16; off; off >>= 1) {
            s0 += __shfl_xor(s0, off);
            s1 += __shfl_xor(s1, off);
        }
        if (h == 0) { out[ve0.y] = s0 + b2s; out[ve1.y] = s1 + b2s; }
    }
    if (p < end) {
        const int2 ve = payload[p];
        float s = edot(ve.x);
        #pragma unroll
        for (int off = 16; off; off >>= 1) s += __shfl_xor(s, off);
        if (h == 0) out[ve.y] = s + b2s;
    }
}

// ---------- Kernel 2b: fallback unsorted edge kernel (if ws too small) ----------
__global__ __launch_bounds__(256) void edge_kernel(
    const int* __restrict__ ei, const unsigned short* __restrict__ C,
    const float* __restrict__ b1, const float* __restrict__ w2,
    const float* __restrict__ b2, float* __restrict__ out, int E)
{
    const int h   = threadIdx.x & 31;
    const int gid = (blockIdx.x * blockDim.x + threadIdx.x) >> 5;
    const int ng  = (gridDim.x * blockDim.x) >> 5;
    const int j0  = h * 8;

    const float4 w2a = *(const float4*)(w2 + j0);
    const float4 w2b = *(const float4*)(w2 + j0 + 4);
    const float4 b1a = *(const float4*)(b1 + j0);
    const float4 b1b = *(const float4*)(b1 + j0 + 4);
    const float  b2s = b2[0];

    auto dot8 = [&](const ushort8& ua, const ushort8& ub) -> float {
        float s;
        s  = fmaxf(bf2f(ua[0]) + bf2f(ub[0]) + b1a.x, 0.f) * w2a.x;
        s += fmaxf(bf2f(ua[1]) + bf2f(ub[1]) + b1a.y, 0.f) * w2a.y;
        s += fmaxf(bf2f(ua[2]) + bf2f(ub[2]) + b1a.z, 0.f) * w2a.z;
        s += fmaxf(bf2f(ua[3]) + bf2f(ub[3]) + b1a.w, 0.f) * w2a.w;
        s += fmaxf(bf2f(ua[4]) + bf2f(ub[4]) + b1b.x, 0.f) * w2b.x;
        s += fmaxf(bf2f(ua[5]) + bf2f(ub[5]) + b1b.y, 0.f) * w2b.y;
        s += fmaxf(bf2f(ua[6]) + bf2f(ub[6]) + b1b.z, 0.f) * w2b.z;
        s += fmaxf(bf2f(ua[7]) + bf2f(ub[7]) + b1b.w, 0.f) * w2b.w;
        return s;
    };

    for (int e = gid; e < E; e += ng) {
        const int u = ei[e], v = ei[E + e];
        const ushort8 ua = *(const ushort8*)(C + (size_t)u * TWOD + j0);
        const ushort8 ub = *(const ushort8*)(C + (size_t)v * TWOD + D + j0);
        float s = dot8(ua, ub);
        #pragma unroll
        for (int off = 16; off; off >>= 1)
            s += __shfl_xor(s, off);
        if (h == 0) out[e] = s + b2s;
    }
}

extern "C" void kernel_launch(void* const* d_in, const int* in_sizes, int n_in,
                              void* d_out, int out_size, void* d_ws, size_t ws_size,
                              hipStream_t stream) {
    const float* z  = (const float*)d_in[0];
    const int*   ei = (const int*)d_in[1];
    const float* w1 = (const float*)d_in[2];
    const float* b1 = (const float*)d_in[3];
    const float* w2 = (const float*)d_in[4];
    const float* b2 = (const float*)d_in[5];
    float* out = (float*)d_out;

    const int M = in_sizes[0] / D;   // 50000 nodes
    const int E = in_sizes[1] / 2;   // 320000 edges

    // ---- workspace layout ----
    unsigned short* C = (unsigned short*)d_ws;              // M*512 bf16 = 51.2 MB
    size_t off = ((size_t)M * TWOD * 2 + 255) & ~(size_t)255;
    int*  counts  = (int*)((char*)d_ws + off); off += (((size_t)M * 4 + 255) & ~(size_t)255);
    int*  offsets = (int*)((char*)d_ws + off); off += (((size_t)(M + 1) * 4 + 255) & ~(size_t)255);
    int*  cursor  = (int*)((char*)d_ws + off); off += (((size_t)M * 4 + 255) & ~(size_t)255);
    int2* payload = (int2*)((char*)d_ws + off); off += (size_t)E * 8;
    const bool use_sort = (off <= ws_size);   // deterministic per fixed ws_size

    unsigned short* WtP = (unsigned short*)d_out;  // 256 KB scratch inside d_out;
                                                   // consumed by GEMM, then overwritten

    wt_conv_kernel<<<512, 256, 0, stream>>>(w1, WtP);

    const int Mblocks = (M + BM - 1) / BM;                 // 391
    const int stripes = (Mblocks + 7) / 8;                 // 49
    node_proj_mfma<<<stripes * 32, 256, 0, stream>>>(z, WtP, C, M, Mblocks);

    if (use_sort) {
        hipMemsetAsync(counts, 0, (size_t)M * 4, stream);
        hist_kernel<<<(E + 255) / 256, 256, 0, stream>>>(ei, counts, E);
        scan_kernel<<<1, 1024, 0, stream>>>(counts, offsets, M);
        hipMemcpyAsync(cursor, offsets, (size_t)M * 4, hipMemcpyDeviceToDevice, stream);
        scatter_kernel<<<(E + 255) / 256, 256, 0, stream>>>(ei, cursor, payload, E);
        edge_grouped_kernel<<<(M * 32 + 255) / 256, 256, 0, stream>>>(
            offsets, payload, C, b1, w2, b2, out, M);
    } else {
        edge_kernel<<<4096, 256, 0, stream>>>(ei, C, b1, w2, b2, out, E);
    }
}

// Round 8
// 125.852 us; speedup vs baseline: 1.4959x; 1.4959x over previous
//
#include <hip/hip_runtime.h>
#include <hip/hip_bf16.h>

#define D 256
#define TWOD 512
#define BM 128
#define BK 32

typedef __attribute__((ext_vector_type(8))) __bf16 bf16x8;
typedef __attribute__((ext_vector_type(4))) float f32x4;
typedef __attribute__((ext_vector_type(8))) unsigned short ushort8;

using as1_u32 = __attribute__((address_space(1))) const unsigned int;
using as3_u32 = __attribute__((address_space(3))) unsigned int;

__device__ __forceinline__ void gload_lds16(const void* g, void* l) {
    __builtin_amdgcn_global_load_lds((as1_u32*)g, (as3_u32*)l, 16, 0, 0);
}

// ---------- helpers ----------
__device__ __forceinline__ float bf2f(unsigned short u) {
    unsigned int x = ((unsigned int)u) << 16;
    return __uint_as_float(x);
}
__device__ __forceinline__ unsigned short f2bf_bits(float f) {
    unsigned int x = __float_as_uint(f);
    unsigned int r = (x + 0x7fffu + ((x >> 16) & 1u)) >> 16;  // RNE
    return (unsigned short)r;
}

// ---------- Kernel 0: w1 (fp32 [256][512]) -> WtP, fragment-packed bf16 ----------
__global__ __launch_bounds__(256) void wt_conv_kernel(
    const float* __restrict__ w1, unsigned short* __restrict__ WtP)
{
    const int s = blockIdx.x * 256 + threadIdx.x;   // 0..131071
    const int o = s >> 9;        // w1 row (output unit)
    const int i = s & 511;       // w1 col (input dim)
    const float v = w1[s];
    const int jj = (i < D) ? o : (D + o);
    const int k  = (i < D) ? i : (i - D);
    const int c16 = jj >> 4, r = jj & 15;
    const int kblk = k >> 5, kin = k & 31;
    const int g = kin >> 3, kj = kin & 7;
    WtP[(size_t)((c16 * 8 + kblk) * 512 + (r + 16 * g) * 8 + kj)] = f2bf_bits(v);
}

// ---------- Kernel 1: MFMA node projection ----------
// A-only LDS (2 x 16KB, double-buffered, global_load_lds), B direct from packed
// WtP (L2-resident, coalesced 1KB per frag load). 4 blocks/CU for TLP.
// XCD-pinned columns: all 4 col-blocks of a row-block on one XCD's L2.
__global__ __launch_bounds__(256, 4) void node_proj_mfma(
    const float* __restrict__ z, const unsigned short* __restrict__ WtP,
    unsigned short* __restrict__ C, int M, int Mblocks)
{
    __shared__ __align__(16) float Abuf[2][BM * BK];  // 2 x 16 KB

    const int bid    = blockIdx.x;
    const int rowblk = (bid >> 5) * 8 + (bid & 7);
    if (rowblk >= Mblocks) return;                 // block-uniform
    const int m0 = rowblk * BM;
    const int cb = ((bid >> 3) & 3) * BM;

    const int t    = threadIdx.x;
    const int lane = t & 63;
    const int w    = t >> 6;

    const int r16 = lane & 15;
    const int g   = lane >> 4;       // 0..3

    const int wm = (w >> 1) * 64;    // wave row offset within tile
    const int wn = (w & 1) * 64;     // wave col offset within tile
    const int c16b = (cb + wn) >> 4;

    f32x4 acc[4][4];
    #pragma unroll
    for (int mt = 0; mt < 4; ++mt)
        #pragma unroll
        for (int nt = 0; nt < 4; ++nt)
            acc[mt][nt] = (f32x4){0.f, 0.f, 0.f, 0.f};

    auto stageA = [&](int buf, int k0) {
        #pragma unroll
        for (int i = 0; i < 4; ++i) {
            const int c = i * 256 + t;
            const int r = c >> 3;
            const int q = c & 7;
            const int col = ((q ^ (r & 7)) << 2);
            const int row = min(m0 + r, M - 1);      // clamp: last-block tail
            const float* gsrc = z + (size_t)row * D + k0 + col;
            float* ldst = &Abuf[buf][(size_t)(i * 256 + w * 64) * 4]; // wave-uniform base
            gload_lds16(gsrc, ldst);
        }
    };

    stageA(0, 0);
    __syncthreads();

    int buf = 0;
    #pragma unroll
    for (int kt = 0; kt < 8; ++kt) {
        if (kt < 7) stageA(buf ^ 1, (kt + 1) * BK);   // prefetch next K-tile

        // B fragments: direct coalesced loads from packed Wt (L2-resident)
        bf16x8 b[4];
        #pragma unroll
        for (int nt = 0; nt < 4; ++nt) {
            const ushort8 bu = *(const ushort8*)(
                WtP + (size_t)(((c16b + nt) * 8 + kt) * 512 + lane * 8));
            b[nt] = __builtin_bit_cast(bf16x8, bu);
        }
        // A fragments (fp32 -> bf16 in-register, swizzled LDS read)
        bf16x8 a[4];
        #pragma unroll
        for (int mt = 0; mt < 4; ++mt) {
            const int rl = wm + mt * 16 + r16;
            const int s = rl & 7;
            const f32x4 f0 = *(const f32x4*)&Abuf[buf][rl * 32 + (((2 * g) ^ s) << 2)];
            const f32x4 f1 = *(const f32x4*)&Abuf[buf][rl * 32 + (((2 * g + 1) ^ s) << 2)];
            bf16x8 tt;
            tt[0] = (__bf16)f0[0]; tt[1] = (__bf16)f0[1];
            tt[2] = (__bf16)f0[2]; tt[3] = (__bf16)f0[3];
            tt[4] = (__bf16)f1[0]; tt[5] = (__bf16)f1[1];
            tt[6] = (__bf16)f1[2]; tt[7] = (__bf16)f1[3];
            a[mt] = tt;
        }

        __builtin_amdgcn_s_setprio(1);
        #pragma unroll
        for (int nt = 0; nt < 4; ++nt)
            #pragma unroll
            for (int mt = 0; mt < 4; ++mt)
                acc[mt][nt] = __builtin_amdgcn_mfma_f32_16x16x32_bf16(
                    b[nt], a[mt], acc[mt][nt], 0, 0, 0);
        __builtin_amdgcn_s_setprio(0);

        __syncthreads();   // drains prefetch vmcnt + retires LDS reads
        buf ^= 1;
    }

    // Store: lane holds 4 consecutive C-columns for one row.
    #pragma unroll
    for (int mt = 0; mt < 4; ++mt) {
        const int row = m0 + wm + mt * 16 + r16;
        if (row < M) {
            #pragma unroll
            for (int nt = 0; nt < 4; ++nt) {
                const int col = cb + wn + nt * 16 + g * 4;
                ushort4 pk;
                pk.x = f2bf_bits(acc[mt][nt][0]);
                pk.y = f2bf_bits(acc[mt][nt][1]);
                pk.z = f2bf_bits(acc[mt][nt][2]);
                pk.w = f2bf_bits(acc[mt][nt][3]);
                *(ushort4*)(C + (size_t)row * TWOD + col) = pk;
            }
        }
    }
}

// ---------- Sort kernels: group edges by source node u ----------
__global__ __launch_bounds__(256) void hist_kernel(
    const int* __restrict__ ei, int* __restrict__ counts, int E)
{
    const int e = blockIdx.x * 256 + threadIdx.x;
    if (e < E) atomicAdd(&counts[ei[e]], 1);
}

// Segment allocation WITHOUT an ordered scan: wave-aggregated atomicAdd.
// Node order in payload is arbitrary; only contiguity matters.
__global__ __launch_bounds__(256) void alloc_kernel(
    const int* __restrict__ counts, int* __restrict__ offsets,
    int* __restrict__ cursor, int* __restrict__ total, int N)
{
    const int u = blockIdx.x * 256 + threadIdx.x;
    const int lane = threadIdx.x & 63;
    const int c = (u < N) ? counts[u] : 0;

    // 64-lane inclusive scan
    int inc = c;
    #pragma unroll
    for (int off = 1; off < 64; off <<= 1) {
        const int tv = __shfl_up(inc, off);
        if (lane >= off) inc += tv;
    }
    const int excl = inc - c;
    const int wavesum = __shfl(inc, 63);

    int base = 0;
    if (lane == 0 && wavesum > 0) base = atomicAdd(total, wavesum);
    base = __shfl(base, 0);

    if (u < N) {
        offsets[u] = base + excl;
        cursor[u]  = base + excl;
    }
}

__global__ __launch_bounds__(256) void scatter_kernel(
    const int* __restrict__ ei, int* __restrict__ cursor,
    int2* __restrict__ payload, int E)
{
    const int e = blockIdx.x * 256 + threadIdx.x;
    if (e < E) {
        const int u = ei[e];
        const int pos = atomicAdd(&cursor[u], 1);
        payload[pos] = make_int2(ei[E + e], e);
    }
}

// ---------- Kernel 2a: grouped edge relu-dot (half-wave per node u) ----------
// A[u] (+ b1) loaded once into regs, reused over all of u's edges.
__global__ __launch_bounds__(256) void edge_grouped_kernel(
    const int* __restrict__ offsets, const int* __restrict__ counts,
    const int2* __restrict__ payload,
    const unsigned short* __restrict__ C, const float* __restrict__ b1,
    const float* __restrict__ w2, const float* __restrict__ b2,
    float* __restrict__ out, int N)
{
    const int h = threadIdx.x & 31;
    const int u = (blockIdx.x * 256 + threadIdx.x) >> 5;
    if (u >= N) return;
    const int cnt = counts[u];
    if (cnt == 0) return;
    const int start = offsets[u];
    const int end   = start + cnt;
    const int j0 = h * 8;

    const ushort8 ua = *(const ushort8*)(C + (size_t)u * TWOD + j0);
    float af[8], wl[8];
    #pragma unroll
    for (int j = 0; j < 8; ++j) {
        af[j] = bf2f(ua[j]) + b1[j0 + j];
        wl[j] = w2[j0 + j];
    }
    const float b2s = b2[0];
    const unsigned short* Cb = C + D;   // B-half base

    auto edot = [&](int v) -> float {
        const ushort8 ub = *(const ushort8*)(Cb + (size_t)v * TWOD + j0);
        float s = 0.f;
        #pragma unroll
        for (int j = 0; j < 8; ++j)
            s += fmaxf(af[j] + bf2f(ub[j]), 0.f) * wl[j];
        return s;
    };

    int p = start;
    for (; p + 2 <= end; p += 2) {
        const int2 ve0 = payload[p];
        const int2 ve1 = payload[p + 1];
        float s0 = edot(ve0.x);
        float s1 = edot(ve1.x);
        #pragma unroll
        for (int off = 16; off; off >>= 1) {
            s0 += __shfl_xor(s0, off);
            s1 += __shfl_xor(s1, off);
        }
        if (h == 0) { out[ve0.y] = s0 + b2s; out[ve1.y] = s1 + b2s; }
    }
    if (p < end) {
        const int2 ve = payload[p];
        float s = edot(ve.x);
        #pragma unroll
        for (int off = 16; off; off >>= 1) s += __shfl_xor(s, off);
        if (h == 0) out[ve.y] = s + b2s;
    }
}

// ---------- Kernel 2b: fallback unsorted edge kernel (if ws too small) ----------
__global__ __launch_bounds__(256) void edge_kernel(
    const int* __restrict__ ei, const unsigned short* __restrict__ C,
    const float* __restrict__ b1, const float* __restrict__ w2,
    const float* __restrict__ b2, float* __restrict__ out, int E)
{
    const int h   = threadIdx.x & 31;
    const int gid = (blockIdx.x * blockDim.x + threadIdx.x) >> 5;
    const int ng  = (gridDim.x * blockDim.x) >> 5;
    const int j0  = h * 8;

    const float4 w2a = *(const float4*)(w2 + j0);
    const float4 w2b = *(const float4*)(w2 + j0 + 4);
    const float4 b1a = *(const float4*)(b1 + j0);
    const float4 b1b = *(const float4*)(b1 + j0 + 4);
    const float  b2s = b2[0];

    auto dot8 = [&](const ushort8& ua, const ushort8& ub) -> float {
        float s;
        s  = fmaxf(bf2f(ua[0]) + bf2f(ub[0]) + b1a.x, 0.f) * w2a.x;
        s += fmaxf(bf2f(ua[1]) + bf2f(ub[1]) + b1a.y, 0.f) * w2a.y;
        s += fmaxf(bf2f(ua[2]) + bf2f(ub[2]) + b1a.z, 0.f) * w2a.z;
        s += fmaxf(bf2f(ua[3]) + bf2f(ub[3]) + b1a.w, 0.f) * w2a.w;
        s += fmaxf(bf2f(ua[4]) + bf2f(ub[4]) + b1b.x, 0.f) * w2b.x;
        s += fmaxf(bf2f(ua[5]) + bf2f(ub[5]) + b1b.y, 0.f) * w2b.y;
        s += fmaxf(bf2f(ua[6]) + bf2f(ub[6]) + b1b.z, 0.f) * w2b.z;
        s += fmaxf(bf2f(ua[7]) + bf2f(ub[7]) + b1b.w, 0.f) * w2b.w;
        return s;
    };

    for (int e = gid; e < E; e += ng) {
        const int u = ei[e], v = ei[E + e];
        const ushort8 ua = *(const ushort8*)(C + (size_t)u * TWOD + j0);
        const ushort8 ub = *(const ushort8*)(C + (size_t)v * TWOD + D + j0);
        float s = dot8(ua, ub);
        #pragma unroll
        for (int off = 16; off; off >>= 1)
            s += __shfl_xor(s, off);
        if (h == 0) out[e] = s + b2s;
    }
}

extern "C" void kernel_launch(void* const* d_in, const int* in_sizes, int n_in,
                              void* d_out, int out_size, void* d_ws, size_t ws_size,
                              hipStream_t stream) {
    const float* z  = (const float*)d_in[0];
    const int*   ei = (const int*)d_in[1];
    const float* w1 = (const float*)d_in[2];
    const float* b1 = (const float*)d_in[3];
    const float* w2 = (const float*)d_in[4];
    const float* b2 = (const float*)d_in[5];
    float* out = (float*)d_out;

    const int M = in_sizes[0] / D;   // 50000 nodes
    const int E = in_sizes[1] / 2;   // 320000 edges

    // ---- workspace layout ----
    unsigned short* C = (unsigned short*)d_ws;              // M*512 bf16 = 51.2 MB
    size_t off = ((size_t)M * TWOD * 2 + 255) & ~(size_t)255;
    int*  counts  = (int*)((char*)d_ws + off); off += (((size_t)M * 4 + 255) & ~(size_t)255);
    int*  offsets = (int*)((char*)d_ws + off); off += (((size_t)M * 4 + 255) & ~(size_t)255);
    int*  cursor  = (int*)((char*)d_ws + off); off += (((size_t)M * 4 + 255) & ~(size_t)255);
    int*  total   = (int*)((char*)d_ws + off); off += 256;
    int2* payload = (int2*)((char*)d_ws + off); off += (size_t)E * 8;
    const bool use_sort = (off <= ws_size);   // deterministic per fixed ws_size

    unsigned short* WtP = (unsigned short*)d_out;  // 256 KB scratch inside d_out;
                                                   // consumed by GEMM, then overwritten

    wt_conv_kernel<<<512, 256, 0, stream>>>(w1, WtP);

    const int Mblocks = (M + BM - 1) / BM;                 // 391
    const int stripes = (Mblocks + 7) / 8;                 // 49
    node_proj_mfma<<<stripes * 32, 256, 0, stream>>>(z, WtP, C, M, Mblocks);

    if (use_sort) {
        hipMemsetAsync(counts, 0, (size_t)M * 4, stream);
        hipMemsetAsync(total, 0, 256, stream);
        hist_kernel<<<(E + 255) / 256, 256, 0, stream>>>(ei, counts, E);
        alloc_kernel<<<(M + 255) / 256, 256, 0, stream>>>(counts, offsets, cursor, total, M);
        scatter_kernel<<<(E + 255) / 256, 256, 0, stream>>>(ei, cursor, payload, E);
        edge_grouped_kernel<<<(M * 32 + 255) / 256, 256, 0, stream>>>(
            offsets, counts, payload, C, b1, w2, b2, out, M);
    } else {
        edge_kernel<<<4096, 256, 0, stream>>>(ei, C, b1, w2, b2, out, E);
    }
}

// Round 9
// 109.548 us; speedup vs baseline: 1.7185x; 1.1488x over previous
//
#include <hip/hip_runtime.h>
#include <hip/hip_bf16.h>

#define D 256
#define TWOD 512

typedef __attribute__((ext_vector_type(8))) __bf16 bf16x8;
typedef __attribute__((ext_vector_type(4))) float f32x4;
typedef __attribute__((ext_vector_type(8))) unsigned short ushort8;

using as1_u32 = __attribute__((address_space(1))) const unsigned int;
using as3_u32 = __attribute__((address_space(3))) unsigned int;

__device__ __forceinline__ void gload_lds16(const void* g, void* l) {
    __builtin_amdgcn_global_load_lds((as1_u32*)g, (as3_u32*)l, 16, 0, 0);
}

// ---------- helpers ----------
__device__ __forceinline__ float bf2f(unsigned short u) {
    unsigned int x = ((unsigned int)u) << 16;
    return __uint_as_float(x);
}
__device__ __forceinline__ unsigned short f2bf_bits(float f) {
    unsigned int x = __float_as_uint(f);
    unsigned int r = (x + 0x7fffu + ((x >> 16) & 1u)) >> 16;  // RNE
    return (unsigned short)r;
}

// ---------- Kernel 0: w1 (fp32 [256][512]) -> WtP, fragment-packed bf16 ----------
// Packed so a wave's B-frag (c16 = jj/16, kblk = k/32) is 512 contiguous shorts:
//   WtP[(c16*8 + kblk)*512 + lane*8 + kj], lane = (jj&15) + 16*((k&31)>>3), kj = k&7
// Col-half ch occupies the contiguous 65536-short range [ch*65536, (ch+1)*65536).
__global__ __launch_bounds__(256) void wt_conv_kernel(
    const float* __restrict__ w1, unsigned short* __restrict__ WtP)
{
    const int s = blockIdx.x * 256 + threadIdx.x;   // 0..131071
    const int o = s >> 9;        // w1 row (output unit)
    const int i = s & 511;       // w1 col (input dim)
    const float v = w1[s];
    const int jj = (i < D) ? o : (D + o);
    const int k  = (i < D) ? i : (i - D);
    const int c16 = jj >> 4, r = jj & 15;
    const int kblk = k >> 5, kin = k & 31;
    const int g = kin >> 3, kj = kin & 7;
    WtP[(size_t)((c16 * 8 + kblk) * 512 + (r + 16 * g) * 8 + kj)] = f2bf_bits(v);
}

// ---------- Kernel 1: persistent-W MFMA node projection ----------
// Grid = 256 blocks (1/CU), 512 threads = 8 waves, LDS 152 KB:
//   Wlds: one col-half of W (256 cols x 256 k bf16, packed) = 128 KB, loaded once
//   Abuf: 3 x (64 rows x 32 k fp32) = 24 KB, counted-vmcnt pipeline
// Block bid: col-half = bid&1, row-tiles rt = (bid>>1) + j*128.
// Wave w owns cols [w*32, w*32+32) of the half; acc = 4(mt) x 2(nt) f32x4.
__global__ __launch_bounds__(512, 2) void node_proj_persist(
    const float* __restrict__ z, const unsigned short* __restrict__ WtP,
    unsigned short* __restrict__ C, int M, int NRT)
{
    __shared__ __align__(16) unsigned short Wlds[65536];   // 128 KB
    __shared__ __align__(16) float Abuf[3][64 * 32];       // 3 x 8 KB

    const int bid  = blockIdx.x;
    const int ch   = bid & 1;
    const int rt0  = bid >> 1;          // 0..127
    const int t    = threadIdx.x;       // 0..511
    const int lane = t & 63;
    const int w    = t >> 6;            // 0..7
    const int r16  = lane & 15;
    const int g    = lane >> 4;         // 0..3

    const int njobs = (NRT - 1 - rt0) / 128 + 1;
    const int S = njobs * 8;            // flat K-step count

    // ---- stage W half into LDS (linear copy of packed WtP slice) ----
    {
        const unsigned short* src = WtP + (size_t)ch * 65536;
        #pragma unroll
        for (int i = 0; i < 16; ++i) {
            const int chunk = i * 512 + t;
            gload_lds16(src + (size_t)chunk * 8,
                        &Wlds[(size_t)(i * 512 + w * 64) * 8]);   // wave-uniform base
        }
    }

    // A stage for flat step s: 64x32 fp32 = 512 chunks of 16B, 1/thread.
    // LDS chunk c = r*8+q (linear) holds global col-chunk q^(r&7) of row r.
    auto stageA = [&](int buf, int s) {
        const int rt = rt0 + (s >> 3) * 128;
        const int k0 = (s & 7) * 32;
        const int r = t >> 3, q = t & 7;
        const int col = (q ^ (r & 7)) << 2;
        const int row = min(rt * 64 + r, M - 1);
        gload_lds16(z + (size_t)row * D + k0 + col,
                    &Abuf[buf][w * 256]);                          // wave-uniform base
    };

    stageA(0, 0);
    if (1 < S) stageA(1, 1);

    int flat = 0, bufc = 0;
    for (int j = 0; j < njobs; ++j) {
        const int rt = rt0 + j * 128;

        f32x4 acc[4][2];
        #pragma unroll
        for (int mt = 0; mt < 4; ++mt)
            #pragma unroll
            for (int nt = 0; nt < 2; ++nt)
                acc[mt][nt] = (f32x4){0.f, 0.f, 0.f, 0.f};

        #pragma unroll
        for (int kt = 0; kt < 8; ++kt) {
            // stage(flat) must be complete; stage(flat+1) may stay in flight.
            if (flat + 1 == S) asm volatile("s_waitcnt vmcnt(0)" ::: "memory");
            else               asm volatile("s_waitcnt vmcnt(1)" ::: "memory");
            __builtin_amdgcn_s_barrier();   // all waves done reading buf (flat-1)%3

            const int s2 = flat + 2;
            if (s2 < S) {
                int buf2 = bufc + 2; if (buf2 >= 3) buf2 -= 3;
                stageA(buf2, s2);           // overwrites buf (flat-1)%3 — retired above
            }

            // B fragments from LDS-resident W (conflict-free consecutive-16B reads)
            bf16x8 b[2];
            #pragma unroll
            for (int nt = 0; nt < 2; ++nt) {
                const ushort8 bu = *(const ushort8*)
                    &Wlds[(size_t)(((w * 2 + nt) * 8 + kt) * 512) + lane * 8];
                b[nt] = __builtin_bit_cast(bf16x8, bu);
            }
            // A fragments (fp32 -> bf16 in-register, swizzled LDS read)
            bf16x8 a[4];
            #pragma unroll
            for (int mt = 0; mt < 4; ++mt) {
                const int rl = mt * 16 + r16;
                const int sw = rl & 7;
                const f32x4 f0 = *(const f32x4*)&Abuf[bufc][rl * 32 + (((2 * g) ^ sw) << 2)];
                const f32x4 f1 = *(const f32x4*)&Abuf[bufc][rl * 32 + (((2 * g + 1) ^ sw) << 2)];
                bf16x8 tt;
                tt[0] = (__bf16)f0[0]; tt[1] = (__bf16)f0[1];
                tt[2] = (__bf16)f0[2]; tt[3] = (__bf16)f0[3];
                tt[4] = (__bf16)f1[0]; tt[5] = (__bf16)f1[1];
                tt[6] = (__bf16)f1[2]; tt[7] = (__bf16)f1[3];
                a[mt] = tt;
            }

            __builtin_amdgcn_s_setprio(1);
            #pragma unroll
            for (int nt = 0; nt < 2; ++nt)
                #pragma unroll
                for (int mt = 0; mt < 4; ++mt)
                    acc[mt][nt] = __builtin_amdgcn_mfma_f32_16x16x32_bf16(
                        b[nt], a[mt], acc[mt][nt], 0, 0, 0);
            __builtin_amdgcn_s_setprio(0);

            ++flat;
            if (++bufc == 3) bufc = 0;
        }

        // Store: lane holds 4 consecutive C-columns for one row.
        #pragma unroll
        for (int mt = 0; mt < 4; ++mt) {
            const int row = rt * 64 + mt * 16 + r16;
            if (row < M) {
                #pragma unroll
                for (int nt = 0; nt < 2; ++nt) {
                    const int col = ch * 256 + w * 32 + nt * 16 + g * 4;
                    ushort4 pk;
                    pk.x = f2bf_bits(acc[mt][nt][0]);
                    pk.y = f2bf_bits(acc[mt][nt][1]);
                    pk.z = f2bf_bits(acc[mt][nt][2]);
                    pk.w = f2bf_bits(acc[mt][nt][3]);
                    *(ushort4*)(C + (size_t)row * TWOD + col) = pk;
                }
            }
        }
    }
}

// ---------- Kernel 2: per-edge relu-dot (half-wave per edge, 4-edge unroll) ----------
__global__ __launch_bounds__(256) void edge_kernel(
    const int* __restrict__ ei, const unsigned short* __restrict__ C,
    const float* __restrict__ b1, const float* __restrict__ w2,
    const float* __restrict__ b2, float* __restrict__ out, int E)
{
    const int h   = threadIdx.x & 31;
    const int gid = (blockIdx.x * blockDim.x + threadIdx.x) >> 5;
    const int ng  = (gridDim.x * blockDim.x) >> 5;
    const int j0  = h * 8;

    const float4 w2a = *(const float4*)(w2 + j0);
    const float4 w2b = *(const float4*)(w2 + j0 + 4);
    const float4 b1a = *(const float4*)(b1 + j0);
    const float4 b1b = *(const float4*)(b1 + j0 + 4);
    const float  b2s = b2[0];

    auto dot8 = [&](const ushort8& ua, const ushort8& ub) -> float {
        float s;
        s  = fmaxf(bf2f(ua[0]) + bf2f(ub[0]) + b1a.x, 0.f) * w2a.x;
        s += fmaxf(bf2f(ua[1]) + bf2f(ub[1]) + b1a.y, 0.f) * w2a.y;
        s += fmaxf(bf2f(ua[2]) + bf2f(ub[2]) + b1a.z, 0.f) * w2a.z;
        s += fmaxf(bf2f(ua[3]) + bf2f(ub[3]) + b1a.w, 0.f) * w2a.w;
        s += fmaxf(bf2f(ua[4]) + bf2f(ub[4]) + b1b.x, 0.f) * w2b.x;
        s += fmaxf(bf2f(ua[5]) + bf2f(ub[5]) + b1b.y, 0.f) * w2b.y;
        s += fmaxf(bf2f(ua[6]) + bf2f(ub[6]) + b1b.z, 0.f) * w2b.z;
        s += fmaxf(bf2f(ua[7]) + bf2f(ub[7]) + b1b.w, 0.f) * w2b.w;
        return s;
    };

    int e = gid;
    for (; e + 3 * ng < E; e += 4 * ng) {
        const int e1 = e + ng, e2 = e + 2 * ng, e3 = e + 3 * ng;
        const int u0 = ei[e],  v0 = ei[E + e];
        const int u1 = ei[e1], v1 = ei[E + e1];
        const int u2 = ei[e2], v2 = ei[E + e2];
        const int u3 = ei[e3], v3 = ei[E + e3];

        const ushort8 ua0 = *(const ushort8*)(C + (size_t)u0 * TWOD + j0);
        const ushort8 ub0 = *(const ushort8*)(C + (size_t)v0 * TWOD + D + j0);
        const ushort8 ua1 = *(const ushort8*)(C + (size_t)u1 * TWOD + j0);
        const ushort8 ub1 = *(const ushort8*)(C + (size_t)v1 * TWOD + D + j0);
        const ushort8 ua2 = *(const ushort8*)(C + (size_t)u2 * TWOD + j0);
        const ushort8 ub2 = *(const ushort8*)(C + (size_t)v2 * TWOD + D + j0);
        const ushort8 ua3 = *(const ushort8*)(C + (size_t)u3 * TWOD + j0);
        const ushort8 ub3 = *(const ushort8*)(C + (size_t)v3 * TWOD + D + j0);

        float s0 = dot8(ua0, ub0);
        float s1 = dot8(ua1, ub1);
        float s2 = dot8(ua2, ub2);
        float s3 = dot8(ua3, ub3);

        #pragma unroll
        for (int off = 16; off; off >>= 1) {
            s0 += __shfl_xor(s0, off);
            s1 += __shfl_xor(s1, off);
            s2 += __shfl_xor(s2, off);
            s3 += __shfl_xor(s3, off);
        }

        if (h == 0) {
            out[e]  = s0 + b2s;
            out[e1] = s1 + b2s;
            out[e2] = s2 + b2s;
            out[e3] = s3 + b2s;
        }
    }
    for (; e < E; e += ng) {
        const int u = ei[e], v = ei[E + e];
        const ushort8 ua = *(const ushort8*)(C + (size_t)u * TWOD + j0);
        const ushort8 ub = *(const ushort8*)(C + (size_t)v * TWOD + D + j0);
        float s = dot8(ua, ub);
        #pragma unroll
        for (int off = 16; off; off >>= 1)
            s += __shfl_xor(s, off);
        if (h == 0) out[e] = s + b2s;
    }
}

extern "C" void kernel_launch(void* const* d_in, const int* in_sizes, int n_in,
                              void* d_out, int out_size, void* d_ws, size_t ws_size,
                              hipStream_t stream) {
    const float* z  = (const float*)d_in[0];
    const int*   ei = (const int*)d_in[1];
    const float* w1 = (const float*)d_in[2];
    const float* b1 = (const float*)d_in[3];
    const float* w2 = (const float*)d_in[4];
    const float* b2 = (const float*)d_in[5];
    float* out = (float*)d_out;

    const int M = in_sizes[0] / D;   // 50000 nodes
    const int E = in_sizes[1] / 2;   // 320000 edges

    unsigned short* C   = (unsigned short*)d_ws;   // M*512 bf16 = 51.2 MB
    unsigned short* WtP = (unsigned short*)d_out;  // 256 KB scratch inside d_out;
                                                   // consumed by GEMM, then overwritten

    wt_conv_kernel<<<512, 256, 0, stream>>>(w1, WtP);

    const int NRT = (M + 63) / 64;   // 782 row tiles of 64
    node_proj_persist<<<256, 512, 0, stream>>>(z, WtP, C, M, NRT);

    edge_kernel<<<4096, 256, 0, stream>>>(ei, C, b1, w2, b2, out, E);
}

// Round 10
// 88.027 us; speedup vs baseline: 2.1386x; 1.2445x over previous
//
#include <hip/hip_runtime.h>
#include <hip/hip_bf16.h>

#define D 256
#define TWOD 512
#define BM 128
#define BK 32

typedef __attribute__((ext_vector_type(8))) __bf16 bf16x8;
typedef __attribute__((ext_vector_type(4))) float f32x4;
typedef __attribute__((ext_vector_type(8))) unsigned short ushort8;

using as1_u32 = __attribute__((address_space(1))) const unsigned int;
using as3_u32 = __attribute__((address_space(3))) unsigned int;

__device__ __forceinline__ void gload_lds16(const void* g, void* l) {
    __builtin_amdgcn_global_load_lds((as1_u32*)g, (as3_u32*)l, 16, 0, 0);
}

// ---------- helpers ----------
__device__ __forceinline__ float bf2f(unsigned short u) {
    unsigned int x = ((unsigned int)u) << 16;
    return __uint_as_float(x);
}
__device__ __forceinline__ unsigned short f2bf_bits(float f) {
    unsigned int x = __float_as_uint(f);
    unsigned int r = (x + 0x7fffu + ((x >> 16) & 1u)) >> 16;  // RNE
    return (unsigned short)r;
}

// ---------- Kernel 0: w1 (fp32 [256][512]) -> WtP, fragment-packed bf16 ----------
// Packed so a wave's B-frag (c16 = jj/16, kblk = k/32) is 512 contiguous shorts:
//   WtP[(c16*8 + kblk)*512 + lane*8 + kj], lane = (jj&15) + 16*((k&31)>>3), kj = k&7
__global__ __launch_bounds__(256) void wt_conv_kernel(
    const float* __restrict__ w1, unsigned short* __restrict__ WtP)
{
    const int s = blockIdx.x * 256 + threadIdx.x;   // 0..131071
    const int o = s >> 9;        // w1 row (output unit)
    const int i = s & 511;       // w1 col (input dim)
    const float v = w1[s];
    const int jj = (i < D) ? o : (D + o);
    const int k  = (i < D) ? i : (i - D);
    const int c16 = jj >> 4, r = jj & 15;
    const int kblk = k >> 5, kin = k & 31;
    const int g = kin >> 3, kj = kin & 7;
    WtP[(size_t)((c16 * 8 + kblk) * 512 + (r + 16 * g) * 8 + kj)] = f2bf_bits(v);
}

// ---------- Kernel 1: MFMA node projection, counted-vmcnt pipeline ----------
// A: 3-buffer LDS (3x16KB), staged 2 K-steps ahead via global_load_lds.
// B: packed WtP (L2-resident), double-buffered in registers 1 step ahead.
// Per step issue: 4 A-stage + 4 B-loads; raw s_barrier with counted vmcnt:
//   top of step kt needs stage(kt) done; ops issued after it = 12 (8 at ends).
// XCD-pinned columns: all 4 col-blocks of a row-block on one XCD's L2.
__global__ __launch_bounds__(256, 3) void node_proj_mfma(
    const float* __restrict__ z, const unsigned short* __restrict__ WtP,
    unsigned short* __restrict__ C, int M, int Mblocks)
{
    __shared__ __align__(16) float Abuf[3][BM * BK];  // 3 x 16 KB

    const int bid    = blockIdx.x;
    const int rowblk = (bid >> 5) * 8 + (bid & 7);
    if (rowblk >= Mblocks) return;                 // block-uniform
    const int m0 = rowblk * BM;
    const int cb = ((bid >> 3) & 3) * BM;

    const int t    = threadIdx.x;
    const int lane = t & 63;
    const int w    = t >> 6;

    const int r16 = lane & 15;
    const int g   = lane >> 4;       // 0..3

    const int wm = (w >> 1) * 64;    // wave row offset within tile
    const int wn = (w & 1) * 64;     // wave col offset within tile
    const int c16b = (cb + wn) >> 4;

    f32x4 acc[4][4];
    #pragma unroll
    for (int mt = 0; mt < 4; ++mt)
        #pragma unroll
        for (int nt = 0; nt < 4; ++nt)
            acc[mt][nt] = (f32x4){0.f, 0.f, 0.f, 0.f};

    auto stageA = [&](int buf, int k0) {
        // A tile: 128x32 f32 = 1024 16B-chunks, 4 per thread (4 VMEM/wave).
        // LDS chunk c = r*8+q holds global col-chunk q^(r&7) of row r.
        #pragma unroll
        for (int i = 0; i < 4; ++i) {
            const int c = i * 256 + t;
            const int r = c >> 3;
            const int q = c & 7;
            const int col = ((q ^ (r & 7)) << 2);
            const int row = min(m0 + r, M - 1);      // clamp: last-block tail
            const float* gsrc = z + (size_t)row * D + k0 + col;
            float* ldst = &Abuf[buf][(size_t)(i * 256 + w * 64) * 4]; // wave-uniform base
            gload_lds16(gsrc, ldst);
        }
    };

    bf16x8 bb[2][4];
    auto loadB = [&](int par, int kt) {
        #pragma unroll
        for (int nt = 0; nt < 4; ++nt) {
            const ushort8 bu = *(const ushort8*)(
                WtP + (size_t)(((c16b + nt) * 8 + kt) * 512 + lane * 8));
            bb[par][nt] = __builtin_bit_cast(bf16x8, bu);
        }
    };

    // Prologue: A(0), A(1) staged; B(0) in regs. Outstanding after: 12.
    stageA(0, 0);
    stageA(1, BK);
    __builtin_amdgcn_sched_barrier(0);
    loadB(0, 0);

    #pragma unroll
    for (int kt = 0; kt < 8; ++kt) {
        // Secure stage(kt); leave stage(kt+1) (+ newer B-loads) in flight.
        if (kt == 0 || kt == 7) asm volatile("s_waitcnt vmcnt(8)" ::: "memory");
        else                    asm volatile("s_waitcnt vmcnt(12)" ::: "memory");
        __builtin_amdgcn_s_barrier();   // waves past here have retired ds_reads of buf (kt+2)%3

        if (kt < 6) stageA((kt + 2) % 3, (kt + 2) * BK);
        __builtin_amdgcn_sched_barrier(0);   // pin: A-stages precede B-loads
        if (kt < 7) loadB((kt + 1) & 1, kt + 1);

        // A fragments (fp32 -> bf16 in-register, swizzled LDS read)
        bf16x8 a[4];
        #pragma unroll
        for (int mt = 0; mt < 4; ++mt) {
            const int rl = wm + mt * 16 + r16;
            const int sw = rl & 7;
            const f32x4 f0 = *(const f32x4*)&Abuf[kt % 3][rl * 32 + (((2 * g) ^ sw) << 2)];
            const f32x4 f1 = *(const f32x4*)&Abuf[kt % 3][rl * 32 + (((2 * g + 1) ^ sw) << 2)];
            bf16x8 tt;
            tt[0] = (__bf16)f0[0]; tt[1] = (__bf16)f0[1];
            tt[2] = (__bf16)f0[2]; tt[3] = (__bf16)f0[3];
            tt[4] = (__bf16)f1[0]; tt[5] = (__bf16)f1[1];
            tt[6] = (__bf16)f1[2]; tt[7] = (__bf16)f1[3];
            a[mt] = tt;
        }

        __builtin_amdgcn_s_setprio(1);
        #pragma unroll
        for (int nt = 0; nt < 4; ++nt)
            #pragma unroll
            for (int mt = 0; mt < 4; ++mt)
                acc[mt][nt] = __builtin_amdgcn_mfma_f32_16x16x32_bf16(
                    bb[kt & 1][nt], a[mt], acc[mt][nt], 0, 0, 0);
        __builtin_amdgcn_s_setprio(0);
    }

    // Store: lane holds 4 consecutive C-columns for one row.
    #pragma unroll
    for (int mt = 0; mt < 4; ++mt) {
        const int row = m0 + wm + mt * 16 + r16;
        if (row < M) {
            #pragma unroll
            for (int nt = 0; nt < 4; ++nt) {
                const int col = cb + wn + nt * 16 + g * 4;
                ushort4 pk;
                pk.x = f2bf_bits(acc[mt][nt][0]);
                pk.y = f2bf_bits(acc[mt][nt][1]);
                pk.z = f2bf_bits(acc[mt][nt][2]);
                pk.w = f2bf_bits(acc[mt][nt][3]);
                *(ushort4*)(C + (size_t)row * TWOD + col) = pk;
            }
        }
    }
}

// ---------- Kernel 2: per-edge relu-dot (half-wave per edge, 4-edge unroll) ----------
__global__ __launch_bounds__(256) void edge_kernel(
    const int* __restrict__ ei, const unsigned short* __restrict__ C,
    const float* __restrict__ b1, const float* __restrict__ w2,
    const float* __restrict__ b2, float* __restrict__ out, int E)
{
    const int h   = threadIdx.x & 31;
    const int gid = (blockIdx.x * blockDim.x + threadIdx.x) >> 5;
    const int ng  = (gridDim.x * blockDim.x) >> 5;
    const int j0  = h * 8;

    const float4 w2a = *(const float4*)(w2 + j0);
    const float4 w2b = *(const float4*)(w2 + j0 + 4);
    const float4 b1a = *(const float4*)(b1 + j0);
    const float4 b1b = *(const float4*)(b1 + j0 + 4);
    const float  b2s = b2[0];

    auto dot8 = [&](const ushort8& ua, const ushort8& ub) -> float {
        float s;
        s  = fmaxf(bf2f(ua[0]) + bf2f(ub[0]) + b1a.x, 0.f) * w2a.x;
        s += fmaxf(bf2f(ua[1]) + bf2f(ub[1]) + b1a.y, 0.f) * w2a.y;
        s += fmaxf(bf2f(ua[2]) + bf2f(ub[2]) + b1a.z, 0.f) * w2a.z;
        s += fmaxf(bf2f(ua[3]) + bf2f(ub[3]) + b1a.w, 0.f) * w2a.w;
        s += fmaxf(bf2f(ua[4]) + bf2f(ub[4]) + b1b.x, 0.f) * w2b.x;
        s += fmaxf(bf2f(ua[5]) + bf2f(ub[5]) + b1b.y, 0.f) * w2b.y;
        s += fmaxf(bf2f(ua[6]) + bf2f(ub[6]) + b1b.z, 0.f) * w2b.z;
        s += fmaxf(bf2f(ua[7]) + bf2f(ub[7]) + b1b.w, 0.f) * w2b.w;
        return s;
    };

    int e = gid;
    for (; e + 3 * ng < E; e += 4 * ng) {
        const int e1 = e + ng, e2 = e + 2 * ng, e3 = e + 3 * ng;
        const int u0 = ei[e],  v0 = ei[E + e];
        const int u1 = ei[e1], v1 = ei[E + e1];
        const int u2 = ei[e2], v2 = ei[E + e2];
        const int u3 = ei[e3], v3 = ei[E + e3];

        const ushort8 ua0 = *(const ushort8*)(C + (size_t)u0 * TWOD + j0);
        const ushort8 ub0 = *(const ushort8*)(C + (size_t)v0 * TWOD + D + j0);
        const ushort8 ua1 = *(const ushort8*)(C + (size_t)u1 * TWOD + j0);
        const ushort8 ub1 = *(const ushort8*)(C + (size_t)v1 * TWOD + D + j0);
        const ushort8 ua2 = *(const ushort8*)(C + (size_t)u2 * TWOD + j0);
        const ushort8 ub2 = *(const ushort8*)(C + (size_t)v2 * TWOD + D + j0);
        const ushort8 ua3 = *(const ushort8*)(C + (size_t)u3 * TWOD + j0);
        const ushort8 ub3 = *(const ushort8*)(C + (size_t)v3 * TWOD + D + j0);

        float s0 = dot8(ua0, ub0);
        float s1 = dot8(ua1, ub1);
        float s2 = dot8(ua2, ub2);
        float s3 = dot8(ua3, ub3);

        #pragma unroll
        for (int off = 16; off; off >>= 1) {
            s0 += __shfl_xor(s0, off);
            s1 += __shfl_xor(s1, off);
            s2 += __shfl_xor(s2, off);
            s3 += __shfl_xor(s3, off);
        }

        if (h == 0) {
            out[e]  = s0 + b2s;
            out[e1] = s1 + b2s;
            out[e2] = s2 + b2s;
            out[e3] = s3 + b2s;
        }
    }
    for (; e < E; e += ng) {
        const int u = ei[e], v = ei[E + e];
        const ushort8 ua = *(const ushort8*)(C + (size_t)u * TWOD + j0);
        const ushort8 ub = *(const ushort8*)(C + (size_t)v * TWOD + D + j0);
        float s = dot8(ua, ub);
        #pragma unroll
        for (int off = 16; off; off >>= 1)
            s += __shfl_xor(s, off);
        if (h == 0) out[e] = s + b2s;
    }
}

extern "C" void kernel_launch(void* const* d_in, const int* in_sizes, int n_in,
                              void* d_out, int out_size, void* d_ws, size_t ws_size,
                              hipStream_t stream) {
    const float* z  = (const float*)d_in[0];
    const int*   ei = (const int*)d_in[1];
    const float* w1 = (const float*)d_in[2];
    const float* b1 = (const float*)d_in[3];
    const float* w2 = (const float*)d_in[4];
    const float* b2 = (const float*)d_in[5];
    float* out = (float*)d_out;

    const int M = in_sizes[0] / D;   // 50000 nodes
    const int E = in_sizes[1] / 2;   // 320000 edges

    unsigned short* C   = (unsigned short*)d_ws;   // M*512 bf16 = 51.2 MB
    unsigned short* WtP = (unsigned short*)d_out;  // 256 KB scratch inside d_out;
                                                   // consumed by GEMM, then overwritten

    wt_conv_kernel<<<512, 256, 0, stream>>>(w1, WtP);

    const int Mblocks = (M + BM - 1) / BM;                 // 391
    const int stripes = (Mblocks + 7) / 8;                 // 49
    node_proj_mfma<<<stripes * 32, 256, 0, stream>>>(z, WtP, C, M, Mblocks);

    edge_kernel<<<4096, 256, 0, stream>>>(ei, C, b1, w2, b2, out, E);
}